// Round 18
// baseline (83.822 us; speedup 1.0000x reference)
//
#include <hip/hip_runtime.h>
#include <hip/hip_bf16.h>
#include <stdint.h>

// RadianceNetwork: 256 independent channel MLPs, B=64.
//   x  = concat(ue[3], view[3], feat[128], nid[1])  -> [64, 135]
//   h1 = relu(x @ W1[c] + b1[c])                    -> [64, 256]
//   h2 = relu(h1 @ W2[c] + b2[c])                   -> [64, 256]
//   o  = h2 @ W3[c] + b3[c]                         -> [64, 816]
// OUTPUT: real components only, fp32 [64][256][408] (R0-R5 forensics).
//
// R16 = m201-style schedule: 16 waves (1024 thr), block-cooperative W
// staging via global_load_lds into a 4-slot ring of 32k x 128n fp32 tiles
// (16 KB each), RAW s_barrier + graduated counted vmcnt (2/1/0) so 2 tiles
// stay in flight ACROSS barriers (__syncthreads would drain vmcnt(0) - the
// R9/R11 mistake). Each wave's DMA = ONE dwordx4 instr = 2 contiguous 512B
// row-slices (8 whole cache lines; R15's wave-private slices were 16
// scattered 64B segments). One barrier/step; slot reuse proven safe
// (issue(t+2) overwrites tile t-2, computed before barrier(t-1)).
// Wave w: n-tile w&7 (16 cols), m-half w>>3 (32 rows), MT=2.
// L1/L2: 2 chunks of 128 cols; L3: 6x128 + 48.
// LDS: h1 32K + {x|h2} 32K + ring 64K = 128 KB dynamic. Grid 256.

#define NCH    256
#define BATCH  64
#define IN_K   135
#define HID    256
#define OUTN   816
#define OUTS   408    // stored real components per (m, c)
#define XPITCHB 336   // bytes per x row (168 bf16; zero-padded k in [135,168))
#define HROWB   512   // bytes per h row (256 bf16, swizzled)
#define NWAVES 16
#define BLOCK  1024
#define SLOTB  16384  // 32 k-rows x 128 n-cols fp32
#define SMEM_BYTES (128 * 1024)

typedef __bf16 bf16x8 __attribute__((ext_vector_type(8)));
typedef float  f32x4  __attribute__((ext_vector_type(4)));
typedef const __attribute__((address_space(1))) void* gas_t;
typedef __attribute__((address_space(3))) void*       las_t;

// One 128(or 48)-col chunk of one layer, k accumulated over KT 32-tiles.
// MFMA 16x16x32 bf16 (layouts HW-verified, m89):
//   A: row m=lane&15, k=(lane>>4)*8+i  (ds_read_b128 from shared h/x LDS)
//   B: col n=lane&15, same k           (ds_read_b32 from ring slot + cvt)
//   D: col n=lane&15, row m=(lane>>4)*4+r
// Ring slot (DMA, linear): fp32 [k 0..31][n 0..127]; wave w's 1 instr
// covers rows 2w,2w+1 (dest = slot + w*1024 + lane*16; src per-lane).
template<int K, int KT, int NSRC, int NCW, bool ASWZ, bool RELU>
__device__ __forceinline__ void chunk_pipe(
    const char*  __restrict__ A,     // LDS activations (x or swizzled h)
    const float* __restrict__ Wg,    // [K][NSRC] weights, channel base
    const float* __restrict__ bg,    // bias, channel base
    char*        __restrict__ Hout,  // LDS out (RELU), swizzled pitch 512B
    float*       __restrict__ Gout,  // global out base (+c*OUTS)
    unsigned long long out_sz, int nc0,
    char* __restrict__ wslots,       // 4 x 16 KB ring
    int wave, int lane)
{
  const int col = lane & 15;
  const int g   = lane >> 4;
  const int nt  = wave & 7;          // n-tile within chunk
  const int mh  = wave >> 3;         // m-half (rows mh*32 .. +31)
  const bool active = (nt * 16) < NCW;

  // chunk entry: all waves done with previous chunk's slots & h-writes
  asm volatile("s_waitcnt lgkmcnt(0)" ::: "memory");
  asm volatile("s_barrier" ::: "memory");

  auto issue = [&](int t) {
    if (t < KT) {
      char* dst = wslots + (t & 3) * SLOTB + wave * 1024;
      const int r = 2 * wave + (lane >> 5);     // tile row 0..31
      int k = t * 32 + r;
      if (K % 32 != 0) k = (k < K) ? k : (K - 1);   // L1 tail: finite clamp
      size_t flat = (size_t)k * NSRC + nc0 + (size_t)(lane & 31) * 4;
      if (NCW < 128) {                          // 48-chunk: stay inside W[c]
        const size_t mx = (size_t)K * NSRC - 4;
        flat = (flat < mx) ? flat : mx;
      }
      __builtin_amdgcn_global_load_lds((gas_t)(Wg + flat), (las_t)dst, 16, 0, 0);
    }
  };

  issue(0); issue(1);                // 2 tiles in flight

  f32x4 acc[2] = {};

#pragma unroll
  for (int kt = 0; kt < KT; ++kt) {
    issue(kt + 2);                   // refill (slot of tile kt-2, long done)
    const int rem = KT - 1 - kt;     // graduated: newest min(2,rem) stay out
    if (rem >= 2)      asm volatile("s_waitcnt vmcnt(2)" ::: "memory");
    else if (rem == 1) asm volatile("s_waitcnt vmcnt(1)" ::: "memory");
    else               asm volatile("s_waitcnt vmcnt(0)" ::: "memory");
    asm volatile("s_barrier" ::: "memory");   // all waves' tile-kt landed

    if (active) {
      const char* slot = wslots + (kt & 3) * SLOTB;
      bf16x8 bfrag;
#pragma unroll
      for (int i = 0; i < 8; ++i) {
        const float w = *(const float*)(slot + (uint32_t)(g * 8 + i) * 512u +
                                        (uint32_t)(nt * 16 + col) * 4u);
        bfrag[i] = (__bf16)w;
      }
      const int kb = kt * 32 + g * 8;
#pragma unroll
      for (int mt = 0; mt < 2; ++mt) {
        const int m = mh * 32 + mt * 16 + col;
        const uint32_t ab = ASWZ
            ? (uint32_t)m * HROWB + (((uint32_t)(kb * 2)) ^ (((uint32_t)m & 7u) << 4))
            : (uint32_t)m * XPITCHB + (uint32_t)(kb * 2);
        const bf16x8 afrag = *(const bf16x8*)(A + ab);
        acc[mt] = __builtin_amdgcn_mfma_f32_16x16x32_bf16(afrag, bfrag, acc[mt], 0, 0, 0);
      }
    }
  }

  // epilogue: bias (+relu->LDS | even-col fp32->global)
  if (active) {
    const int n = nc0 + nt * 16 + col;
    const float bias = bg[n];
#pragma unroll
    for (int mt = 0; mt < 2; ++mt) {
#pragma unroll
      for (int r = 0; r < 4; ++r) {
        float v = acc[mt][r] + bias;
        const int m = mh * 32 + mt * 16 + g * 4 + r;
        if (RELU) {
          v = v > 0.f ? v : 0.f;
          *(__bf16*)(Hout + (uint32_t)m * HROWB +
                     (((uint32_t)(n * 2)) ^ (((uint32_t)m & 7u) << 4))) = (__bf16)v;
        } else if ((n & 1) == 0) {           // real component only
          const unsigned long long oi =
              (unsigned long long)m * (NCH * OUTS) + (unsigned long long)(n >> 1);
          if (oi < out_sz) Gout[oi] = v;
        }
      }
    }
  }
}

__global__ __launch_bounds__(BLOCK) void radiance_mlp_kernel(
    const float* __restrict__ ue,   const float* __restrict__ view,
    const float* __restrict__ feat, const int*   __restrict__ ids,
    const float* __restrict__ W1, const float* __restrict__ b1,
    const float* __restrict__ W2, const float* __restrict__ b2,
    const float* __restrict__ W3, const float* __restrict__ b3,
    float* __restrict__ out, unsigned long long out_sz)
{
  extern __shared__ __attribute__((aligned(16))) char smem[];
  char* buf0   = smem;               // h1: 32 KB (swizzled pitch 512B)
  char* buf1   = smem + 32768;       // x (pitch 336B) then h2: 32 KB
  char* wslots = smem + 65536;       // 4 x 16 KB W ring

  const int c    = blockIdx.x;       // one full-batch block per channel
  const int tid  = threadIdx.x;
  const int wave = tid >> 6;
  const int lane = tid & 63;

  // Stage input x -> bf16 in buf1 (pitch 336B), zero-pad k in [135,168).
  for (int idx = tid; idx < BATCH * (XPITCHB / 2); idx += BLOCK) {
    const int m = idx / (XPITCHB / 2);
    const int k = idx - m * (XPITCHB / 2);
    float v = 0.0f;
    if (k < 3)         v = ue[m * 3 + k];
    else if (k < 6)    v = view[m * 3 + (k - 3)];
    else if (k < 134)  v = feat[m * 128 + (k - 6)];
    else if (k == 134) v = ((float)ids[m] - 1.0f) * (1.0f / 63.0f);
    *(__bf16*)(buf1 + (uint32_t)m * XPITCHB + 2u * (uint32_t)k) = (__bf16)v;
  }
  __syncthreads();

  // L1: x(buf1) -> h1(buf0).  K=135 (5 k-tiles), N=256 in 2 chunks.
  const float* W1c = W1 + (size_t)c * IN_K * HID;
  const float* b1c = b1 + (size_t)c * HID;
  chunk_pipe<IN_K, 5, HID, 128, false, true>(buf1, W1c, b1c, buf0, nullptr, 0, 0,
                                             wslots, wave, lane);
  chunk_pipe<IN_K, 5, HID, 128, false, true>(buf1, W1c, b1c, buf0, nullptr, 0, 128,
                                             wslots, wave, lane);

  // L2: h1(buf0) -> h2(buf1).  K=256 (8 k-tiles), N=256 in 2 chunks.
  const float* W2c = W2 + (size_t)c * HID * HID;
  const float* b2c = b2 + (size_t)c * HID;
  chunk_pipe<HID, 8, HID, 128, true, true>(buf0, W2c, b2c, buf1, nullptr, 0, 0,
                                           wslots, wave, lane);
  chunk_pipe<HID, 8, HID, 128, true, true>(buf0, W2c, b2c, buf1, nullptr, 0, 128,
                                           wslots, wave, lane);

  // L3: h2(buf1) -> out.  K=256, N=816 = 6 x 128 + 48.
  const float* W3c = W3 + (size_t)c * HID * OUTN;
  const float* b3c = b3 + (size_t)c * OUTN;
  float* outc = out + (size_t)c * OUTS;
  for (int cc = 0; cc < 6; ++cc)
    chunk_pipe<HID, 8, OUTN, 128, true, false>(buf1, W3c, b3c, nullptr, outc,
                                               out_sz, cc * 128, wslots, wave, lane);
  chunk_pipe<HID, 8, OUTN, 48, true, false>(buf1, W3c, b3c, nullptr, outc,
                                            out_sz, 768, wslots, wave, lane);
}

extern "C" void kernel_launch(void* const* d_in, const int* in_sizes, int n_in,
                              void* d_out, int out_size, void* d_ws, size_t ws_size,
                              hipStream_t stream) {
  const float* ue   = (const float*)d_in[0];
  const float* view = (const float*)d_in[1];
  const float* feat = (const float*)d_in[2];
  const int*   ids  = (const int*)d_in[3];
  const float* W1   = (const float*)d_in[4];
  const float* b1   = (const float*)d_in[5];
  const float* W2   = (const float*)d_in[6];
  const float* b2   = (const float*)d_in[7];
  const float* W3   = (const float*)d_in[8];
  const float* b3   = (const float*)d_in[9];
  float* out = (float*)d_out;

  // Host-side attribute set (not a stream op; graph-capture-safe, idempotent).
  hipFuncSetAttribute(reinterpret_cast<const void*>(radiance_mlp_kernel),
                      hipFuncAttributeMaxDynamicSharedMemorySize, SMEM_BYTES);

  hipLaunchKernelGGL(radiance_mlp_kernel, dim3(NCH), dim3(BLOCK), SMEM_BYTES,
                     stream, ue, view, feat, ids, W1, b1, W2, b2, W3, b3,
                     out, (unsigned long long)out_size);
}